// Round 11
// baseline (58.913 us; speedup 1.0000x reference)
//
#include <hip/hip_runtime.h>
#include <math.h>

// LIFNeuronFDE: fractional-order LIF with Grunwald-Letnikov memory.
//   v^{k+1} = 2*(I_k - v^k) - sum_{j=0}^{k} c_{k+1-j} v^{(j)},  v^{(0)} = v0
//   spike_k = sigmoid(5*(v^{k+1} - 1))
// T=32, B=32, N=32768.  Linear-map form: v_{k+1} = b[k]*v0 + sum_j a[k][j] I_j.
//
// R10 result: nt stores -> 48.6us (write stream no longer evicts I from L3).
// Residual analysis: VALU absolute time ~32us > write floor ~21us -> now
// VALU-overhead-bound. VGPR=72 @ 29% occupancy = the CSE'd fp64 temps are
// AGPR-split again (operand-move tax ~16us over the ~16us ideal).
// R11 change (on R10): __launch_bounds__(256,2) lifts the arch-VGPR cap to
// 256; convert If->fp64 ONCE upfront (Id[64] = 128 VGPRs, lives in arch
// VGPRs, no AGPR moves, no re-cvt). fp64 fma sequence per accumulator
// unchanged (b[k]*v0 init, ascending j; cvt exact) -> bitwise-identical
// output (absmax margin thin: 0.0176/0.02).

#define T_STEPS 32
#define BN (32 * 32768)              // B*N = 1,048,576 elements
#define PAIRS (BN / 2)               // 524,288 float2 work items

typedef float f32x2 __attribute__((ext_vector_type(2)));

struct LinMap {
    double a[T_STEPS][T_STEPS];      // a[k][j]: coeff of I_j in v_{k+1} (j<=k)
    double b[T_STEPS];               // b[k]:    coeff of v0  in v_{k+1}
};

constexpr LinMap make_linmap() {
    // GL coefficients: c_0=1, c_j = (1 - 1.5/j) c_{j-1}
    double c[T_STEPS + 1] = {};
    c[0] = 1.0;
    for (int j = 1; j <= T_STEPS; ++j) c[j] = c[j - 1] * (1.0 - 1.5 / (double)j);

    // vc[k][m]: coefficient of basis element m in v_k (m=0 -> v0, m=1+j -> I_j)
    double vc[T_STEPS + 1][T_STEPS + 1] = {};
    vc[0][0] = 1.0;

    LinMap r{};
    for (int k = 0; k < T_STEPS; ++k) {
        // v_{k+1} = 2*I_k - 2*v_k - sum_{j=0}^{k} c[k+1-j] * v_j
        for (int m = 0; m <= T_STEPS; ++m) {
            double acc = -2.0 * vc[k][m];
            for (int j = 0; j <= k; ++j) acc -= c[k + 1 - j] * vc[j][m];
            vc[k + 1][m] = acc;
        }
        vc[k + 1][1 + k] += 2.0;

        r.b[k] = vc[k + 1][0];
        for (int j = 0; j < T_STEPS; ++j) r.a[k][j] = vc[k + 1][1 + j];
    }
    return r;
}

constexpr LinMap CM = make_linmap();

// Row K: s = b[K]*v0 + sum_{j=0}^{K} a[K][j]*Id[j] (fp64, ascending j),
// then spike = sigmoid(5*(s-1)). All Id[] indices are compile-time literals.
template<int K>
__device__ __forceinline__ void fde_rows(const double (&Idx)[T_STEPS],
                                         const double (&Idy)[T_STEPS],
                                         const double v0x, const double v0y,
                                         f32x2* __restrict__ out2,
                                         const int idx)
{
    if constexpr (K < T_STEPS) {
        double sx = CM.b[K] * v0x;
        double sy = CM.b[K] * v0y;
        #pragma unroll
        for (int j = 0; j <= K; ++j) {
            sx = fma(CM.a[K][j], Idx[j], sx);
            sy = fma(CM.a[K][j], Idy[j], sy);
        }
        const float ax = (float)(-5.0 * (sx - 1.0));
        const float ay = (float)(-5.0 * (sy - 1.0));
        f32x2 sp;
        sp.x = 1.0f / (1.0f + __expf(ax));
        sp.y = 1.0f / (1.0f + __expf(ay));
        // Non-temporal store: zero-reuse output stays out of L3 so I stays
        // resident across replays (R10's win).
        __builtin_nontemporal_store(sp, &out2[(size_t)K * PAIRS + idx]);

        fde_rows<K + 1>(Idx, Idy, v0x, v0y, out2, idx);
    }
}

__global__ __launch_bounds__(256, 2) void lif_fde_kernel(
    const float* __restrict__ I,
    const float* __restrict__ v0,
    float* __restrict__ out)
{
    const int idx = blockIdx.x * blockDim.x + threadIdx.x;   // [0, PAIRS)

    const float2* __restrict__ I2   = (const float2*)I;
    const float2* __restrict__ v02  = (const float2*)v0;
    f32x2* __restrict__        out2 = (f32x2*)out;

    // Stage all of I (32 independent dwordx2 loads -> one pipelined latency
    // hit), then convert to fp64 ONCE. Under the 256-VGPR cap Id[] stays in
    // arch VGPRs: no AGPR operand moves, no repeated cvt.
    float2 If[T_STEPS];
    #pragma unroll
    for (int k = 0; k < T_STEPS; ++k) {
        If[k] = I2[(size_t)k * PAIRS + idx];
    }

    double Idx[T_STEPS], Idy[T_STEPS];
    #pragma unroll
    for (int k = 0; k < T_STEPS; ++k) {
        Idx[k] = (double)If[k].x;
        Idy[k] = (double)If[k].y;
    }

    const float2 v0f = v02[idx];
    const double v0x = (double)v0f.x;
    const double v0y = (double)v0f.y;

    fde_rows<0>(Idx, Idy, v0x, v0y, out2, idx);
}

extern "C" void kernel_launch(void* const* d_in, const int* in_sizes, int n_in,
                              void* d_out, int out_size, void* d_ws, size_t ws_size,
                              hipStream_t stream) {
    const float* I  = (const float*)d_in[0];   // (T, B, N) fp32
    const float* v0 = (const float*)d_in[1];   // (B, N) fp32
    float* out = (float*)d_out;                // (T, B, N) fp32

    dim3 block(256);
    dim3 grid(PAIRS / 256);                    // 2048 blocks, exact fit
    lif_fde_kernel<<<grid, block, 0, stream>>>(I, v0, out);
}

// Round 12
// 56.617 us; speedup vs baseline: 1.0406x; 1.0406x over previous
//
#include <hip/hip_runtime.h>
#include <math.h>

// LIFNeuronFDE: fractional-order LIF with Grunwald-Letnikov memory.
//   v^{k+1} = 2*(I_k - v^k) - sum_{j=0}^{k} c_{k+1-j} v^{(j)},  v^{(0)} = v0
//   spike_k = sigmoid(5*(v^{k+1} - 1))
// T=32, B=32, N=32768.  Linear-map form: v_{k+1} = b[k]*v0 + sum_j a[k][j] I_j.
//
// R10 (best, 48.6us): float2 gather + lazy cvt + nt stores.
// R11 lesson: upfront cvt + launch_bounds(256,2) -> identical counters,
// slower. Lazy cvt wins; allocator is immovable from source.
// R12 (this): profiled VALU ~31us absolute vs ~18us ideal => fp64 issue is
// the largest consumer. Exploit error structure: |a[k][j]| grows with lag
// k-j (impulse response ~1.55^lag). Small-lag terms (lag<8, |a|<=44) are
// computed in fp32 and folded into the fp64 accumulator once per row.
// Worst-case added output error ~6e-4 (margin 2.4e-3); errors do NOT
// propagate (each row independent). fp64 FMAs 528->300, 228 now fp32.

#define T_STEPS 32
#define BN (32 * 32768)              // B*N = 1,048,576 elements
#define PAIRS (BN / 2)               // 524,288 float2 work items
#define LMIX 8                       // lags < LMIX computed in fp32

typedef float f32x2 __attribute__((ext_vector_type(2)));

struct LinMap {
    double a[T_STEPS][T_STEPS];      // a[k][j]: coeff of I_j in v_{k+1} (j<=k)
    double b[T_STEPS];               // b[k]:    coeff of v0  in v_{k+1}
    float  af[T_STEPS][T_STEPS];     // fp32 copies for the small-lag terms
};

constexpr LinMap make_linmap() {
    // GL coefficients: c_0=1, c_j = (1 - 1.5/j) c_{j-1}
    double c[T_STEPS + 1] = {};
    c[0] = 1.0;
    for (int j = 1; j <= T_STEPS; ++j) c[j] = c[j - 1] * (1.0 - 1.5 / (double)j);

    // vc[k][m]: coefficient of basis element m in v_k (m=0 -> v0, m=1+j -> I_j)
    double vc[T_STEPS + 1][T_STEPS + 1] = {};
    vc[0][0] = 1.0;

    LinMap r{};
    for (int k = 0; k < T_STEPS; ++k) {
        // v_{k+1} = 2*I_k - 2*v_k - sum_{j=0}^{k} c[k+1-j] * v_j
        for (int m = 0; m <= T_STEPS; ++m) {
            double acc = -2.0 * vc[k][m];
            for (int j = 0; j <= k; ++j) acc -= c[k + 1 - j] * vc[j][m];
            vc[k + 1][m] = acc;
        }
        vc[k + 1][1 + k] += 2.0;

        r.b[k] = vc[k + 1][0];
        for (int j = 0; j < T_STEPS; ++j) {
            r.a[k][j]  = vc[k + 1][1 + j];
            r.af[k][j] = (float)vc[k + 1][1 + j];
        }
    }
    return r;
}

constexpr LinMap CM = make_linmap();

// Row K: s = b[K]*v0 + [fp64: j <= K-LMIX] + [fp32 partial: j > K-LMIX],
// then spike = sigmoid(5*(s-1)). All If[] indices are compile-time literals.
template<int K>
__device__ __forceinline__ void fde_rows(const float2 (&If)[T_STEPS],
                                         const double v0x, const double v0y,
                                         f32x2* __restrict__ out2,
                                         const int idx)
{
    if constexpr (K < T_STEPS) {
        // fp64 j-range: [0, JSPLIT); fp32 j-range: [JSPLIT, K]
        constexpr int JSPLIT = (K >= LMIX) ? (K - LMIX + 1) : 0;

        double sx = CM.b[K] * v0x;
        double sy = CM.b[K] * v0y;
        #pragma unroll
        for (int j = 0; j < JSPLIT; ++j) {       // large-lag: fp64 (lazy cvt)
            sx = fma(CM.a[K][j], (double)If[j].x, sx);
            sy = fma(CM.a[K][j], (double)If[j].y, sy);
        }
        float fx = 0.0f, fy = 0.0f;              // small-lag: fp32 partial
        #pragma unroll
        for (int j = JSPLIT; j <= K; ++j) {
            fx = fmaf(CM.af[K][j], If[j].x, fx);
            fy = fmaf(CM.af[K][j], If[j].y, fy);
        }
        sx += (double)fx;
        sy += (double)fy;

        const float ax = (float)(-5.0 * (sx - 1.0));
        const float ay = (float)(-5.0 * (sy - 1.0));
        f32x2 sp;
        sp.x = 1.0f / (1.0f + __expf(ax));
        sp.y = 1.0f / (1.0f + __expf(ay));
        // Non-temporal store (R10's win: faster write path, zero-reuse data).
        __builtin_nontemporal_store(sp, &out2[(size_t)K * PAIRS + idx]);

        fde_rows<K + 1>(If, v0x, v0y, out2, idx);
    }
}

__global__ __launch_bounds__(256) void lif_fde_kernel(
    const float* __restrict__ I,
    const float* __restrict__ v0,
    float* __restrict__ out)
{
    const int idx = blockIdx.x * blockDim.x + threadIdx.x;   // [0, PAIRS)

    const float2* __restrict__ I2   = (const float2*)I;
    const float2* __restrict__ v02  = (const float2*)v0;
    f32x2* __restrict__        out2 = (f32x2*)out;

    // Stage all of I for this pair in fp32 registers (exact), issued as 32
    // independent dwordx2 loads -> one pipelined latency hit.
    float2 If[T_STEPS];
    #pragma unroll
    for (int k = 0; k < T_STEPS; ++k) {
        If[k] = I2[(size_t)k * PAIRS + idx];
    }

    const float2 v0f = v02[idx];
    const double v0x = (double)v0f.x;
    const double v0y = (double)v0f.y;

    fde_rows<0>(If, v0x, v0y, out2, idx);
}

extern "C" void kernel_launch(void* const* d_in, const int* in_sizes, int n_in,
                              void* d_out, int out_size, void* d_ws, size_t ws_size,
                              hipStream_t stream) {
    const float* I  = (const float*)d_in[0];   // (T, B, N) fp32
    const float* v0 = (const float*)d_in[1];   // (B, N) fp32
    float* out = (float*)d_out;                // (T, B, N) fp32

    dim3 block(256);
    dim3 grid(PAIRS / 256);                    // 2048 blocks, exact fit
    lif_fde_kernel<<<grid, block, 0, stream>>>(I, v0, out);
}